// Round 31
// baseline (83.084 us; speedup 1.0000x reference)
//
#include <hip/hip_runtime.h>
#include <hip/hip_bf16.h>
#include <stdint.h>

typedef __attribute__((ext_vector_type(8))) short short8;
typedef __attribute__((ext_vector_type(4))) float f32x4;

#define N_HEADS 12
#define HD      64
#define BSZ     8
#define TSZ     1024
#define CSZ     768
#define MSZ     (BSZ * TSZ)   /* 8192 */
#define N3      (3 * CSZ)     /* 2304 */

static __device__ __forceinline__ unsigned short f2bf(float f) {
    union { float f; uint32_t u; } v; v.f = f;
    uint32_t r = v.u + 0x7fffu + ((v.u >> 16) & 1u);
    return (unsigned short)(r >> 16);
}

// async global->LDS, 16B per lane, LDS dest = wave-uniform base + lane*16
static __device__ __forceinline__ void gload16(const unsigned short* g,
                                               unsigned short* l) {
    __builtin_amdgcn_global_load_lds(
        (const __attribute__((address_space(1))) void*)g,
        (__attribute__((address_space(3))) void*)l, 16, 0, 0);
}

// ---------------- fused fp32 -> bf16 conversion (8 elems/thread) ----------
__global__ void cvt2_f32_to_bf16(const float* __restrict__ x, int nx,
                                 const float* __restrict__ W, int nw,
                                 unsigned short* __restrict__ xb,
                                 unsigned short* __restrict__ wb) {
    int i = (blockIdx.x * blockDim.x + threadIdx.x) * 8;
    const float* s; unsigned short* d; int j;
    if (i < nx) { s = x; d = xb; j = i; }
    else        { s = W; d = wb; j = i - nx; if (j + 7 >= nw) return; }
    float4 f0 = *reinterpret_cast<const float4*>(s + j);
    float4 f1 = *reinterpret_cast<const float4*>(s + j + 4);
    ushort4 u0, u1;
    u0.x = f2bf(f0.x); u0.y = f2bf(f0.y); u0.z = f2bf(f0.z); u0.w = f2bf(f0.w);
    u1.x = f2bf(f1.x); u1.y = f2bf(f1.y); u1.z = f2bf(f1.z); u1.w = f2bf(f1.w);
    *reinterpret_cast<ushort4*>(d + j) = u0;
    *reinterpret_cast<ushort4*>(d + j + 4) = u1;
}

// ---------------- QKV projection GEMM (128x64 tile, 3 blk/CU, no tail) ----
// r23's counted-vmcnt skeleton but N-tile 64: grid 64x36 = 2304 blocks at
// 3 blocks/CU (48KB LDS) = 768 slots -> EXACTLY 3 residency rounds (the
// 128x128 grid was 2.25 rounds -> makespan 3 rounds, ~25% tail idle seen
// as 28% avg occupancy). 8 waves of 32x32 (acc[2][2]); STAGE = 3 gloads
// per thread -> phase-end vmcnt(3) retires t+1, keeps t+2 in flight.
__global__ __launch_bounds__(512, 3) void qkv_gemm(
    const unsigned short* __restrict__ xb,   // [8192][768] bf16
    const unsigned short* __restrict__ wb,   // [2304][768] bf16
    const float* __restrict__ bias,          // [2304] f32
    unsigned short* __restrict__ qo,
    unsigned short* __restrict__ ko,
    unsigned short* __restrict__ vto)
{
    __shared__ unsigned short A0[128 * 64];
    __shared__ unsigned short A1[128 * 64];
    __shared__ unsigned short B0[64 * 64];
    __shared__ unsigned short B1[64 * 64];
    const int tid = threadIdx.x;
    const int lane = tid & 63;
    const int w = tid >> 6;
    const int lr = lane >> 4, lc = lane & 15;
    const int xcd = blockIdx.x & 7, idx = blockIdx.x >> 3;   // idx 0..287
    const int bm = xcd * 8 + (idx & 7);     // 0..63 (x-slice 1.5MB/XCD L2-fit)
    const int bn = idx >> 3;                // 0..35
    const int m0 = bm * 128;
    const int n0 = bn * 64;
    const int wrow = (w >> 1) * 32;         // 4 M-waves
    const int wcol = (w & 1) * 32;          // 2 N-waves

    // A: 1024 chunks (2/thread); B: 512 chunks (1/thread). XOR involution.
    const int r1 = tid >> 3, c1 = ((tid & 7) ^ (r1 & 7)) * 8;
    const int r2 = 64 + r1,  c2 = ((tid & 7) ^ (r2 & 7)) * 8;

    f32x4 acc[2][2] = {};

#define STAGE(T, LA, LB)                                                   \
    do {                                                                   \
        gload16(xb + (size_t)(m0 + r1) * CSZ + (T) * 64 + c1, (LA) + tid * 8); \
        gload16(xb + (size_t)(m0 + r2) * CSZ + (T) * 64 + c2, (LA) + 4096 + tid * 8); \
        gload16(wb + (size_t)(n0 + r1) * CSZ + (T) * 64 + c1, (LB) + tid * 8); \
    } while (0)

#define PHASE(T, CA, CB, DO_STAGE, VMN)                                    \
    do {                                                                   \
        short8 af[2][2], bf[2][2];                                         \
        _Pragma("unroll")                                                  \
        for (int mi = 0; mi < 2; ++mi)                                     \
            _Pragma("unroll")                                              \
            for (int ks = 0; ks < 2; ++ks) {                               \
                int row = wrow + mi * 16 + lc;                             \
                af[mi][ks] = *reinterpret_cast<const short8*>(             \
                    (CA) + row * 64 + (((ks * 4 + lr) ^ (row & 7)) * 8));  \
            }                                                              \
        _Pragma("unroll")                                                  \
        for (int ni = 0; ni < 2; ++ni)                                     \
            _Pragma("unroll")                                              \
            for (int ks = 0; ks < 2; ++ks) {                               \
                int row = wcol + ni * 16 + lc;                             \
                bf[ni][ks] = *reinterpret_cast<const short8*>(             \
                    (CB) + row * 64 + (((ks * 4 + lr) ^ (row & 7)) * 8));  \
            }                                                              \
        asm volatile("s_waitcnt lgkmcnt(0)" ::: "memory");                 \
        __builtin_amdgcn_sched_barrier(0);                                 \
        __builtin_amdgcn_s_barrier();      /* all waves done reading */    \
        if (DO_STAGE) STAGE((T) + 2, CA, CB);                              \
        __builtin_amdgcn_s_setprio(1);                                     \
        _Pragma("unroll")                                                  \
        for (int ks = 0; ks < 2; ++ks)                                     \
            _Pragma("unroll")                                              \
            for (int mi = 0; mi < 2; ++mi)                                 \
                _Pragma("unroll")                                          \
                for (int ni = 0; ni < 2; ++ni)                             \
                    acc[mi][ni] = __builtin_amdgcn_mfma_f32_16x16x32_bf16( \
                        af[mi][ks], bf[ni][ks], acc[mi][ni], 0, 0, 0);     \
        __builtin_amdgcn_s_setprio(0);                                     \
        asm volatile("s_waitcnt vmcnt(" #VMN ")" ::: "memory");            \
        __builtin_amdgcn_s_barrier();      /* publish next tile */         \
        __builtin_amdgcn_sched_barrier(0);                                 \
    } while (0)

    STAGE(0, A0, B0);
    STAGE(1, A1, B1);
    asm volatile("s_waitcnt vmcnt(3)" ::: "memory");
    __builtin_amdgcn_s_barrier();

    #pragma unroll 1
    for (int tt = 0; tt < 10; tt += 2) {
        PHASE(tt,     A0, B0, true, 3);
        PHASE(tt + 1, A1, B1, true, 3);
    }
    PHASE(10, A0, B0, false, 0);   // tail: drain tile 11
    PHASE(11, A1, B1, false, 0);
#undef STAGE
#undef PHASE

    const int sec = n0 / CSZ;       // 64 | 768 -> uniform per block
    const int nb = n0 - sec * CSZ;
    #pragma unroll
    for (int ni = 0; ni < 2; ++ni) {
        int ncol = wcol + ni * 16 + lc;     // 0..63
        int nn = nb + ncol;
        float badd = bias[n0 + ncol];
        int h = nn >> 6, d = nn & 63;
        #pragma unroll
        for (int mi = 0; mi < 2; ++mi) {
            int mbase = m0 + wrow + mi * 16 + lr * 4;
            int bb = mbase >> 10, t0 = mbase & 1023;
            int plane = bb * N_HEADS + h;
            if (sec == 0) {
                #pragma unroll
                for (int r = 0; r < 4; ++r)
                    qo[((size_t)plane * TSZ + t0 + r) * HD + d] =
                        f2bf((acc[mi][ni][r] + badd) * 0.125f);
            } else if (sec == 1) {
                #pragma unroll
                for (int r = 0; r < 4; ++r)
                    ko[((size_t)plane * TSZ + t0 + r) * HD + d] =
                        f2bf(acc[mi][ni][r] + badd);
            } else {
                ushort4 pk;
                pk.x = f2bf(acc[mi][ni][0] + badd);
                pk.y = f2bf(acc[mi][ni][1] + badd);
                pk.z = f2bf(acc[mi][ni][2] + badd);
                pk.w = f2bf(acc[mi][ni][3] + badd);
                *reinterpret_cast<ushort4*>(
                    vto + ((size_t)plane * HD + d) * TSZ + t0) = pk;
            }
        }
    }
}

// ---------------- causal-ReLU attention (r28 EXACT: 3-perm balance) -------
__global__ __launch_bounds__(256, 3) void attn_kernel(
    const unsigned short* __restrict__ q,    // [96][1024][64] bf16 (pre-scaled)
    const unsigned short* __restrict__ k,    // [96][1024][64] bf16
    const unsigned short* __restrict__ vt,   // [96][64][1024] bf16
    float* __restrict__ out)                 // [8][1024][768] f32
{
    __shared__ unsigned short Kl[2][64 * 64];
    __shared__ unsigned short Vl[2][64 * 64];
    __shared__ unsigned short Sl[4][32 * 64];
    const int tid = threadIdx.x;
    const int wid = tid >> 6;
    const int lane = tid & 63;
    const int lr = lane >> 4, lc = lane & 15;
    const int xcd = blockIdx.x & 7, slot = blockIdx.x >> 3;   // slot 0..95
    const int bh = xcd * 12 + (slot >> 3);   // 12 heads per XCD (L2-local)
    const int s_ = slot & 7, rnd = slot >> 5;
    int pr;                                   // balanced pr per round
    if (rnd == 0)      pr = s_;
    else if (rnd == 1) pr = (s_ + 3) & 7;
    else               pr = (5440239u >> (3 * s_)) & 7;  // {7,5,3,1,0,6,4,2}
    const int jj = pr * 2 + (wid >> 1);      // this wave's 64-row q-tile
    const int b = bh / N_HEADS, h = bh - b * N_HEADS;
    const size_t base = (size_t)bh * (TSZ * HD);
    const size_t vbase = (size_t)bh * (HD * TSZ);
    const int qrow0 = jj * 64 + (wid & 1) * 32;
    unsigned short* sm = Sl[wid];
    const int ntb = pr * 2 + 2;              // block step count
    const int ntw = jj + 1;                  // this wave's step count

    short8 aq[2][2];
    #pragma unroll
    for (int ks = 0; ks < 2; ++ks)
        #pragma unroll
        for (int qi = 0; qi < 2; ++qi)
            aq[ks][qi] = *reinterpret_cast<const short8*>(
                q + base + (size_t)(qrow0 + qi * 16 + lc) * HD + ks * 32 + lr * 8);

    f32x4 y[2][4] = {};

#define STAGEKV(KT, BI)                                                     \
    do {                                                                    \
        _Pragma("unroll")                                                   \
        for (int i = 0; i < 2; ++i) {                                       \
            int c = i * 256 + tid;                                          \
            int r_ = c >> 3;                                                \
            int c8 = (c & 7) ^ (r_ & 7);                                    \
            gload16(k + base + (size_t)((KT) * 64 + r_) * HD + c8 * 8,      \
                    Kl[BI] + c * 8);                                        \
            gload16(vt + vbase + (size_t)r_ * TSZ + (KT) * 64 + c8 * 8,     \
                    Vl[BI] + c * 8);                                        \
        }                                                                   \
    } while (0)

    STAGEKV(0, 0);
    __syncthreads();

    for (int kt = 0; kt < ntb; ++kt) {
        const int bi = kt & 1;
        if (kt + 1 < ntb) STAGEKV(kt + 1, bi ^ 1);   // prefetch over compute
        if (kt < ntw) {
            const unsigned short* Kb = Kl[bi];
            const unsigned short* Vb = Vl[bi];
            f32x4 st[4][2] = {};
            #pragma unroll
            for (int ks = 0; ks < 2; ++ks) {
                short8 ak[4];
                #pragma unroll
                for (int ki = 0; ki < 4; ++ki)
                    ak[ki] = *reinterpret_cast<const short8*>(
                        Kb + (ki * 16 + lc) * 64 + (((ks * 4 + lr) ^ (lc & 7)) * 8));
                __builtin_amdgcn_s_setprio(1);
                #pragma unroll
                for (int ki = 0; ki < 4; ++ki)
                    #pragma unroll
                    for (int qi = 0; qi < 2; ++qi)
                        st[ki][qi] = __builtin_amdgcn_mfma_f32_16x16x32_bf16(
                            ak[ki], aq[ks][qi], st[ki][qi], 0, 0, 0);
                __builtin_amdgcn_s_setprio(0);
            }
            const bool diag = (kt == jj);
            const int kv0 = kt * 64;
            #pragma unroll
            for (int ki = 0; ki < 4; ++ki) {
                #pragma unroll
                for (int qi = 0; qi < 2; ++qi) {
                    float vv[4];
                    #pragma unroll
                    for (int r = 0; r < 4; ++r) {
                        float s = fmaxf(st[ki][qi][r], 0.0f);
                        if (diag && (kv0 + ki * 16 + lr * 4 + r > qrow0 + qi * 16 + lc))
                            s = 0.0f;
                        vv[r] = s;
                    }
                    __hip_bfloat162 p0 = __float22bfloat162_rn(make_float2(vv[0], vv[1]));
                    __hip_bfloat162 p1 = __float22bfloat162_rn(make_float2(vv[2], vv[3]));
                    uint2 pk;
                    pk.x = *reinterpret_cast<unsigned*>(&p0);
                    pk.y = *reinterpret_cast<unsigned*>(&p1);
                    int row = qi * 16 + lc;
                    int chunk = (2 * ki + (lr >> 1)) ^ (row & 7);
                    *reinterpret_cast<uint2*>(
                        sm + row * 64 + chunk * 8 + (lr & 1) * 4) = pk;
                }
            }
            #pragma unroll
            for (int ks = 0; ks < 2; ++ks) {
                short8 as[2], bv[4];
                #pragma unroll
                for (int qi = 0; qi < 2; ++qi)
                    as[qi] = *reinterpret_cast<const short8*>(
                        sm + (qi * 16 + lc) * 64 + (((ks * 4 + lr) ^ (lc & 7)) * 8));
                #pragma unroll
                for (int di = 0; di < 4; ++di)
                    bv[di] = *reinterpret_cast<const short8*>(
                        Vb + (di * 16 + lc) * 64 + (((ks * 4 + lr) ^ (lc & 7)) * 8));
                __builtin_amdgcn_s_setprio(1);
                #pragma unroll
                for (int qi = 0; qi < 2; ++qi)
                    #pragma unroll
                    for (int di = 0; di < 4; ++di)
                        y[qi][di] = __builtin_amdgcn_mfma_f32_16x16x32_bf16(
                            as[qi], bv[di], y[qi][di], 0, 0, 0);
                __builtin_amdgcn_s_setprio(0);
            }
        }
        __syncthreads();   // all 4 waves, every step (uniform ntb)
    }
#undef STAGEKV

    #pragma unroll
    for (int qi = 0; qi < 2; ++qi)
        #pragma unroll
        for (int di = 0; di < 4; ++di)
            #pragma unroll
            for (int r = 0; r < 4; ++r) {
                int t = qrow0 + qi * 16 + lr * 4 + r;
                int d = di * 16 + lc;
                out[((size_t)b * TSZ + t) * CSZ + h * HD + d] = y[qi][di][r];
            }
}

extern "C" void kernel_launch(void* const* d_in, const int* in_sizes, int n_in,
                              void* d_out, int out_size, void* d_ws, size_t ws_size,
                              hipStream_t stream) {
    const float* x    = (const float*)d_in[0];
    const float* W    = (const float*)d_in[1];
    const float* bias = (const float*)d_in[2];
    float* out = (float*)d_out;

    unsigned short* xb  = (unsigned short*)d_ws;                 // 8192*768
    unsigned short* wb  = xb + (size_t)MSZ * CSZ;                // 2304*768
    unsigned short* qo  = wb + (size_t)N3 * CSZ;                 // 96*1024*64
    unsigned short* ko  = qo + (size_t)MSZ * CSZ;
    unsigned short* vto = ko + (size_t)MSZ * CSZ;

    const int nx = MSZ * CSZ;   // 6291456
    const int nw = N3 * CSZ;    // 1769472
    cvt2_f32_to_bf16<<<(nx + nw) / 2048, 256, 0, stream>>>(x, nx, W, nw, xb, wb);
    qkv_gemm<<<dim3(2304), 512, 0, stream>>>(xb, wb, bias, qo, ko, vto);
    attn_kernel<<<dim3(768), 256, 0, stream>>>(qo, ko, vto, out);
}

// Round 32
// 78.762 us; speedup vs baseline: 1.0549x; 1.0549x over previous
//
#include <hip/hip_runtime.h>
#include <hip/hip_bf16.h>
#include <stdint.h>

typedef __attribute__((ext_vector_type(8))) short short8;
typedef __attribute__((ext_vector_type(4))) float f32x4;

#define N_HEADS 12
#define HD      64
#define BSZ     8
#define TSZ     1024
#define CSZ     768
#define MSZ     (BSZ * TSZ)   /* 8192 */
#define N3      (3 * CSZ)     /* 2304 */

static __device__ __forceinline__ unsigned short f2bf(float f) {
    union { float f; uint32_t u; } v; v.f = f;
    uint32_t r = v.u + 0x7fffu + ((v.u >> 16) & 1u);
    return (unsigned short)(r >> 16);
}

// async global->LDS, 16B per lane, LDS dest = wave-uniform base + lane*16
static __device__ __forceinline__ void gload16(const unsigned short* g,
                                               unsigned short* l) {
    __builtin_amdgcn_global_load_lds(
        (const __attribute__((address_space(1))) void*)g,
        (__attribute__((address_space(3))) void*)l, 16, 0, 0);
}

// ---------------- fused fp32 -> bf16 conversion (8 elems/thread) ----------
__global__ void cvt2_f32_to_bf16(const float* __restrict__ x, int nx,
                                 const float* __restrict__ W, int nw,
                                 unsigned short* __restrict__ xb,
                                 unsigned short* __restrict__ wb) {
    int i = (blockIdx.x * blockDim.x + threadIdx.x) * 8;
    const float* s; unsigned short* d; int j;
    if (i < nx) { s = x; d = xb; j = i; }
    else        { s = W; d = wb; j = i - nx; if (j + 7 >= nw) return; }
    float4 f0 = *reinterpret_cast<const float4*>(s + j);
    float4 f1 = *reinterpret_cast<const float4*>(s + j + 4);
    ushort4 u0, u1;
    u0.x = f2bf(f0.x); u0.y = f2bf(f0.y); u0.z = f2bf(f0.z); u0.w = f2bf(f0.w);
    u1.x = f2bf(f1.x); u1.y = f2bf(f1.y); u1.z = f2bf(f1.z); u1.w = f2bf(f1.w);
    *reinterpret_cast<ushort4*>(d + j) = u0;
    *reinterpret_cast<ushort4*>(d + j + 4) = u1;
}

// ---------------- QKV projection GEMM (r23/r28 EXACT: 8-wave counted dbuf)
__global__ __launch_bounds__(512, 2) void qkv_gemm(
    const unsigned short* __restrict__ xb,   // [8192][768] bf16
    const unsigned short* __restrict__ wb,   // [2304][768] bf16
    const float* __restrict__ bias,          // [2304] f32
    unsigned short* __restrict__ qo,
    unsigned short* __restrict__ ko,
    unsigned short* __restrict__ vto)
{
    __shared__ unsigned short A0[128 * 64];
    __shared__ unsigned short B0[128 * 64];
    __shared__ unsigned short A1[128 * 64];
    __shared__ unsigned short B1[128 * 64];
    const int tid = threadIdx.x;
    const int lane = tid & 63;
    const int w = tid >> 6;
    const int lr = lane >> 4, lc = lane & 15;
    const int xcd = blockIdx.x & 7, idx = blockIdx.x >> 3;   // idx 0..143
    const int bm = xcd * 8 + (idx & 7);     // 0..63
    const int bn = idx >> 3;                // 0..17
    const int m0 = bm * 128;
    const int n0 = bn * 128;
    const int wrow = (w >> 2) * 64;         // 2 M-waves
    const int wcol = (w & 3) * 32;          // 4 N-waves

    const int r1 = tid >> 3, c1 = ((tid & 7) ^ (r1 & 7)) * 8;
    const int r2 = 64 + r1,  c2 = ((tid & 7) ^ (r2 & 7)) * 8;

    f32x4 acc[4][2] = {};

#define STAGE(T, LA, LB)                                                   \
    do {                                                                   \
        gload16(xb + (size_t)(m0 + r1) * CSZ + (T) * 64 + c1, (LA) + tid * 8); \
        gload16(xb + (size_t)(m0 + r2) * CSZ + (T) * 64 + c2, (LA) + 4096 + tid * 8); \
        gload16(wb + (size_t)(n0 + r1) * CSZ + (T) * 64 + c1, (LB) + tid * 8); \
        gload16(wb + (size_t)(n0 + r2) * CSZ + (T) * 64 + c2, (LB) + 4096 + tid * 8); \
    } while (0)

#define PHASE(T, CA, CB, DO_STAGE, VMN)                                    \
    do {                                                                   \
        short8 af[4][2], bf[2][2];                                         \
        _Pragma("unroll")                                                  \
        for (int mi = 0; mi < 4; ++mi)                                     \
            _Pragma("unroll")                                              \
            for (int ks = 0; ks < 2; ++ks) {                               \
                int row = wrow + mi * 16 + lc;                             \
                af[mi][ks] = *reinterpret_cast<const short8*>(             \
                    (CA) + row * 64 + (((ks * 4 + lr) ^ (row & 7)) * 8));  \
            }                                                              \
        _Pragma("unroll")                                                  \
        for (int ni = 0; ni < 2; ++ni)                                     \
            _Pragma("unroll")                                              \
            for (int ks = 0; ks < 2; ++ks) {                               \
                int row = wcol + ni * 16 + lc;                             \
                bf[ni][ks] = *reinterpret_cast<const short8*>(             \
                    (CB) + row * 64 + (((ks * 4 + lr) ^ (row & 7)) * 8));  \
            }                                                              \
        asm volatile("s_waitcnt lgkmcnt(0)" ::: "memory");                 \
        __builtin_amdgcn_sched_barrier(0);                                 \
        __builtin_amdgcn_s_barrier();      /* all waves done reading */    \
        if (DO_STAGE) STAGE((T) + 2, CA, CB);                              \
        __builtin_amdgcn_s_setprio(1);                                     \
        _Pragma("unroll")                                                  \
        for (int ks = 0; ks < 2; ++ks)                                     \
            _Pragma("unroll")                                              \
            for (int mi = 0; mi < 4; ++mi)                                 \
                _Pragma("unroll")                                          \
                for (int ni = 0; ni < 2; ++ni)                             \
                    acc[mi][ni] = __builtin_amdgcn_mfma_f32_16x16x32_bf16( \
                        af[mi][ks], bf[ni][ks], acc[mi][ni], 0, 0, 0);     \
        __builtin_amdgcn_s_setprio(0);                                     \
        asm volatile("s_waitcnt vmcnt(" #VMN ")" ::: "memory");            \
        __builtin_amdgcn_s_barrier();      /* publish next tile */         \
        __builtin_amdgcn_sched_barrier(0);                                 \
    } while (0)

    STAGE(0, A0, B0);
    STAGE(1, A1, B1);
    asm volatile("s_waitcnt vmcnt(4)" ::: "memory");
    __builtin_amdgcn_s_barrier();

    #pragma unroll 1
    for (int tt = 0; tt < 10; tt += 2) {
        PHASE(tt,     A0, B0, true, 4);
        PHASE(tt + 1, A1, B1, true, 4);
    }
    PHASE(10, A0, B0, false, 0);   // tail: drain tile 11
    PHASE(11, A1, B1, false, 0);
#undef STAGE
#undef PHASE

    const int sec = n0 / CSZ;
    const int nb = n0 - sec * CSZ;
    #pragma unroll
    for (int ni = 0; ni < 2; ++ni) {
        int ncol = wcol + ni * 16 + lc;
        int nn = nb + ncol;
        float badd = bias[n0 + ncol];
        int h = nn >> 6, d = nn & 63;
        #pragma unroll
        for (int mi = 0; mi < 4; ++mi) {
            int mbase = m0 + wrow + mi * 16 + lr * 4;
            int bb = mbase >> 10, t0 = mbase & 1023;
            int plane = bb * N_HEADS + h;
            if (sec == 0) {
                #pragma unroll
                for (int r = 0; r < 4; ++r)
                    qo[((size_t)plane * TSZ + t0 + r) * HD + d] =
                        f2bf((acc[mi][ni][r] + badd) * 0.125f);
            } else if (sec == 1) {
                #pragma unroll
                for (int r = 0; r < 4; ++r)
                    ko[((size_t)plane * TSZ + t0 + r) * HD + d] =
                        f2bf(acc[mi][ni][r] + badd);
            } else {
                ushort4 pk;
                pk.x = f2bf(acc[mi][ni][0] + badd);
                pk.y = f2bf(acc[mi][ni][1] + badd);
                pk.z = f2bf(acc[mi][ni][2] + badd);
                pk.w = f2bf(acc[mi][ni][3] + badd);
                *reinterpret_cast<ushort4*>(
                    vto + ((size_t)plane * HD + d) * TSZ + t0) = pk;
            }
        }
    }
}

// ---------------- causal-ReLU attention (r28 EXACT: 3-perm balance) -------
__global__ __launch_bounds__(256, 3) void attn_kernel(
    const unsigned short* __restrict__ q,    // [96][1024][64] bf16 (pre-scaled)
    const unsigned short* __restrict__ k,    // [96][1024][64] bf16
    const unsigned short* __restrict__ vt,   // [96][64][1024] bf16
    float* __restrict__ out)                 // [8][1024][768] f32
{
    __shared__ unsigned short Kl[2][64 * 64];
    __shared__ unsigned short Vl[2][64 * 64];
    __shared__ unsigned short Sl[4][32 * 64];
    const int tid = threadIdx.x;
    const int wid = tid >> 6;
    const int lane = tid & 63;
    const int lr = lane >> 4, lc = lane & 15;
    const int xcd = blockIdx.x & 7, slot = blockIdx.x >> 3;   // slot 0..95
    const int bh = xcd * 12 + (slot >> 3);   // 12 heads per XCD (L2-local)
    const int s_ = slot & 7, rnd = slot >> 5;
    int pr;                                   // balanced pr per round
    if (rnd == 0)      pr = s_;
    else if (rnd == 1) pr = (s_ + 3) & 7;
    else               pr = (5440239u >> (3 * s_)) & 7;  // {7,5,3,1,0,6,4,2}
    const int jj = pr * 2 + (wid >> 1);      // this wave's 64-row q-tile
    const int b = bh / N_HEADS, h = bh - b * N_HEADS;
    const size_t base = (size_t)bh * (TSZ * HD);
    const size_t vbase = (size_t)bh * (HD * TSZ);
    const int qrow0 = jj * 64 + (wid & 1) * 32;
    unsigned short* sm = Sl[wid];
    const int ntb = pr * 2 + 2;              // block step count
    const int ntw = jj + 1;                  // this wave's step count

    short8 aq[2][2];
    #pragma unroll
    for (int ks = 0; ks < 2; ++ks)
        #pragma unroll
        for (int qi = 0; qi < 2; ++qi)
            aq[ks][qi] = *reinterpret_cast<const short8*>(
                q + base + (size_t)(qrow0 + qi * 16 + lc) * HD + ks * 32 + lr * 8);

    f32x4 y[2][4] = {};

#define STAGEKV(KT, BI)                                                     \
    do {                                                                    \
        _Pragma("unroll")                                                   \
        for (int i = 0; i < 2; ++i) {                                       \
            int c = i * 256 + tid;                                          \
            int r_ = c >> 3;                                                \
            int c8 = (c & 7) ^ (r_ & 7);                                    \
            gload16(k + base + (size_t)((KT) * 64 + r_) * HD + c8 * 8,      \
                    Kl[BI] + c * 8);                                        \
            gload16(vt + vbase + (size_t)r_ * TSZ + (KT) * 64 + c8 * 8,     \
                    Vl[BI] + c * 8);                                        \
        }                                                                   \
    } while (0)

    STAGEKV(0, 0);
    __syncthreads();

    for (int kt = 0; kt < ntb; ++kt) {
        const int bi = kt & 1;
        if (kt + 1 < ntb) STAGEKV(kt + 1, bi ^ 1);   // prefetch over compute
        if (kt < ntw) {
            const unsigned short* Kb = Kl[bi];
            const unsigned short* Vb = Vl[bi];
            f32x4 st[4][2] = {};
            #pragma unroll
            for (int ks = 0; ks < 2; ++ks) {
                short8 ak[4];
                #pragma unroll
                for (int ki = 0; ki < 4; ++ki)
                    ak[ki] = *reinterpret_cast<const short8*>(
                        Kb + (ki * 16 + lc) * 64 + (((ks * 4 + lr) ^ (lc & 7)) * 8));
                __builtin_amdgcn_s_setprio(1);
                #pragma unroll
                for (int ki = 0; ki < 4; ++ki)
                    #pragma unroll
                    for (int qi = 0; qi < 2; ++qi)
                        st[ki][qi] = __builtin_amdgcn_mfma_f32_16x16x32_bf16(
                            ak[ki], aq[ks][qi], st[ki][qi], 0, 0, 0);
                __builtin_amdgcn_s_setprio(0);
            }
            const bool diag = (kt == jj);
            const int kv0 = kt * 64;
            #pragma unroll
            for (int ki = 0; ki < 4; ++ki) {
                #pragma unroll
                for (int qi = 0; qi < 2; ++qi) {
                    float vv[4];
                    #pragma unroll
                    for (int r = 0; r < 4; ++r) {
                        float s = fmaxf(st[ki][qi][r], 0.0f);
                        if (diag && (kv0 + ki * 16 + lr * 4 + r > qrow0 + qi * 16 + lc))
                            s = 0.0f;
                        vv[r] = s;
                    }
                    __hip_bfloat162 p0 = __float22bfloat162_rn(make_float2(vv[0], vv[1]));
                    __hip_bfloat162 p1 = __float22bfloat162_rn(make_float2(vv[2], vv[3]));
                    uint2 pk;
                    pk.x = *reinterpret_cast<unsigned*>(&p0);
                    pk.y = *reinterpret_cast<unsigned*>(&p1);
                    int row = qi * 16 + lc;
                    int chunk = (2 * ki + (lr >> 1)) ^ (row & 7);
                    *reinterpret_cast<uint2*>(
                        sm + row * 64 + chunk * 8 + (lr & 1) * 4) = pk;
                }
            }
            #pragma unroll
            for (int ks = 0; ks < 2; ++ks) {
                short8 as[2], bv[4];
                #pragma unroll
                for (int qi = 0; qi < 2; ++qi)
                    as[qi] = *reinterpret_cast<const short8*>(
                        sm + (qi * 16 + lc) * 64 + (((ks * 4 + lr) ^ (lc & 7)) * 8));
                #pragma unroll
                for (int di = 0; di < 4; ++di)
                    bv[di] = *reinterpret_cast<const short8*>(
                        Vb + (di * 16 + lc) * 64 + (((ks * 4 + lr) ^ (lc & 7)) * 8));
                __builtin_amdgcn_s_setprio(1);
                #pragma unroll
                for (int qi = 0; qi < 2; ++qi)
                    #pragma unroll
                    for (int di = 0; di < 4; ++di)
                        y[qi][di] = __builtin_amdgcn_mfma_f32_16x16x32_bf16(
                            as[qi], bv[di], y[qi][di], 0, 0, 0);
                __builtin_amdgcn_s_setprio(0);
            }
        }
        __syncthreads();   // all 4 waves, every step (uniform ntb)
    }
#undef STAGEKV

    #pragma unroll
    for (int qi = 0; qi < 2; ++qi)
        #pragma unroll
        for (int di = 0; di < 4; ++di)
            #pragma unroll
            for (int r = 0; r < 4; ++r) {
                int t = qrow0 + qi * 16 + lr * 4 + r;
                int d = di * 16 + lc;
                out[((size_t)b * TSZ + t) * CSZ + h * HD + d] = y[qi][di][r];
            }
}

extern "C" void kernel_launch(void* const* d_in, const int* in_sizes, int n_in,
                              void* d_out, int out_size, void* d_ws, size_t ws_size,
                              hipStream_t stream) {
    const float* x    = (const float*)d_in[0];
    const float* W    = (const float*)d_in[1];
    const float* bias = (const float*)d_in[2];
    float* out = (float*)d_out;

    unsigned short* xb  = (unsigned short*)d_ws;                 // 8192*768
    unsigned short* wb  = xb + (size_t)MSZ * CSZ;                // 2304*768
    unsigned short* qo  = wb + (size_t)N3 * CSZ;                 // 96*1024*64
    unsigned short* ko  = qo + (size_t)MSZ * CSZ;
    unsigned short* vto = ko + (size_t)MSZ * CSZ;

    const int nx = MSZ * CSZ;   // 6291456
    const int nw = N3 * CSZ;    // 1769472
    cvt2_f32_to_bf16<<<(nx + nw) / 2048, 256, 0, stream>>>(x, nx, W, nw, xb, wb);
    qkv_gemm<<<dim3(1152), 512, 0, stream>>>(xb, wb, bias, qo, ko, vto);
    attn_kernel<<<dim3(768), 256, 0, stream>>>(qo, ko, vto, out);
}